// Round 9
// baseline (225.360 us; speedup 1.0000x reference)
//
#include <hip/hip_runtime.h>

#define SEQ 4096
#define DM 1024
#define NH 16
#define HD 64

typedef __attribute__((ext_vector_type(8))) short short8;
typedef __attribute__((ext_vector_type(4))) short short4v;
typedef __attribute__((ext_vector_type(2))) short short2v;
typedef __attribute__((ext_vector_type(4))) float float4v;
typedef __attribute__((ext_vector_type(4))) int int4v;

__device__ __forceinline__ short f2bf(float f) {
    union { float f; unsigned u; } v; v.f = f;
    unsigned u = v.u;
    return (short)((u + 0x7fffu + ((u >> 16) & 1u)) >> 16);
}
// pack two fp32 -> dword of two round-half-up bf16 (3 VALU: add, add, perm)
__device__ __forceinline__ int pk2bf(float a, float b) {
    union { float f; unsigned u; } x, y; x.f = a; y.f = b;
    return (int)__builtin_amdgcn_perm(y.u + 0x8000u, x.u + 0x8000u, 0x07060302u);
}

__device__ __forceinline__ void gload_lds16(const void* g, void* l) {
    __builtin_amdgcn_global_load_lds(
        (const __attribute__((address_space(1))) void*)g,
        (__attribute__((address_space(3))) void*)l, 16, 0, 0);
}

// ---------- prep: cast x -> bf16  +  transpose/cast both weights (one launch) ----------
// flat grid: [0,4096) cast_x ; [4096,7168) Wqkv^T (Q-cols prescaled) ; [7168,8192) Wout^T
__global__ __launch_bounds__(256) void prep_kernel(const float* __restrict__ x,
                                                   const float* __restrict__ Wqkv,
                                                   const float* __restrict__ Wout,
                                                   short* __restrict__ xb,
                                                   short* __restrict__ wqkvT,
                                                   short* __restrict__ woutT,
                                                   float qscale) {
    __shared__ float tile[32][33];
    int id = blockIdx.x;
    int tid = threadIdx.x;
    if (id < 4096) {
        int i = id * 256 + tid;            // n4 = SEQ*DM/4 = 1048576 exactly
        float4v v = ((const float4v*)x)[i];
        short4v o;
        o[0] = f2bf(v[0]); o[1] = f2bf(v[1]); o[2] = f2bf(v[2]); o[3] = f2bf(v[3]);
        ((short4v*)xb)[i] = o;
        return;
    }
    const float* in; short* outp; int H, W, sr; float sc; int gx, gy;
    if (id < 4096 + 3072) {
        int i2 = id - 4096;
        in = Wqkv; outp = wqkvT; H = DM; W = 3 * DM; sr = DM; sc = qscale;
        gx = i2 % 96; gy = i2 / 96;
    } else {
        int i3 = id - 7168;
        in = Wout; outp = woutT; H = DM; W = DM; sr = 0; sc = 1.0f;
        gx = i3 % 32; gy = i3 / 32;
    }
    int bx = gx * 32, by = gy * 32;
    int tx = tid & 31, ty = tid >> 5;      // 32 x 8
#pragma unroll
    for (int i = 0; i < 32; i += 8)
        tile[ty + i][tx] = in[(by + ty + i) * W + bx + tx];
    __syncthreads();
#pragma unroll
    for (int i = 0; i < 32; i += 8) {
        int orow = bx + ty + i;
        float s = (orow < sr) ? sc : 1.0f;
        outp[orow * H + by + tx] = f2bf(tile[tx][ty + i] * s);
    }
}

// ------------- GEMM1: xb[4096,1024] x wqkvT[3072,1024] -> qkv (Q,K cols) + vt (V cols) --
// m97 structure, 128x128 tile. For n0 >= 2048 the epilogue writes V directly into the
// swizzled vt[h*64+d][swz(s)] layout (4 consecutive s per lane -> one short4 store);
// swz preserves s&3, so swz(base+r) = swz(base)+r. transpose_v kernel eliminated.
__global__ __launch_bounds__(256) void gemm_qkv(const short* __restrict__ A,
                                                const short* __restrict__ BT,
                                                short* __restrict__ C,
                                                short* __restrict__ vt) {
    const int K = DM, N = 3 * DM;
    __shared__ short As[128 * 32];
    __shared__ short Bs[128 * 32];
    int tid  = threadIdx.x;
    int m0   = blockIdx.y * 128;
    int n0   = blockIdx.x * 128;
    int w    = tid >> 6, lane = tid & 63;
    int wm   = w >> 1,  wn   = w & 1;
    int quad = lane >> 4, l15 = lane & 15;
    int srow = lane >> 2;
    int scol = (lane & 3) * 8;

    float4v acc[4][4];
#pragma unroll
    for (int mi = 0; mi < 4; mi++)
#pragma unroll
        for (int ni = 0; ni < 4; ni++)
            acc[mi][ni] = {0.f, 0.f, 0.f, 0.f};

    for (int k0 = 0; k0 < K; k0 += 32) {
        __syncthreads();
#pragma unroll
        for (int t = 0; t < 2; t++) {
            int chunk = w * 2 + t;
            int r = chunk * 16 + srow;
            gload_lds16(&A[(m0 + r) * K + k0 + scol], &As[chunk * 16 * 32]);
            gload_lds16(&BT[(n0 + r) * K + k0 + scol], &Bs[chunk * 16 * 32]);
        }
        __syncthreads();
        short8 a[4], b[4];
#pragma unroll
        for (int mi = 0; mi < 4; mi++)
            a[mi] = *(const short8*)&As[(wm * 64 + mi * 16 + l15) * 32 + quad * 8];
#pragma unroll
        for (int ni = 0; ni < 4; ni++)
            b[ni] = *(const short8*)&Bs[(wn * 64 + ni * 16 + l15) * 32 + quad * 8];
#pragma unroll
        for (int mi = 0; mi < 4; mi++)
#pragma unroll
            for (int ni = 0; ni < 4; ni++)
                acc[mi][ni] = __builtin_amdgcn_mfma_f32_16x16x32_bf16(a[mi], b[ni], acc[mi][ni], 0, 0, 0);
    }

    if (n0 < 2 * DM) {
        // Q,K columns -> qkv row-major
#pragma unroll
        for (int mi = 0; mi < 4; mi++)
#pragma unroll
            for (int ni = 0; ni < 4; ni++)
#pragma unroll
                for (int r = 0; r < 4; r++) {
                    int row = m0 + wm * 64 + mi * 16 + quad * 4 + r;
                    int col = n0 + wn * 64 + ni * 16 + l15;
                    C[row * N + col] = f2bf(acc[mi][ni][r]);
                }
    } else {
        // V columns -> vt[(h*64+d)][swz(s)], s = output row, dcol = col-2048
#pragma unroll
        for (int mi = 0; mi < 4; mi++)
#pragma unroll
            for (int ni = 0; ni < 4; ni++) {
                int dcol = n0 - 2 * DM + wn * 64 + ni * 16 + l15;
                int base = m0 + wm * 64 + mi * 16 + quad * 4;      // base&3 == 0
                int swzb = (base & ~31) | ((base & 12) << 1) | ((base & 16) >> 2);
                short4v pv;
#pragma unroll
                for (int r = 0; r < 4; r++)
                    pv[r] = f2bf(acc[mi][ni][r]);
                *(short4v*)&vt[dcol * SEQ + swzb] = pv;
            }
    }
}

// ------------- GEMM2: 64x128 tile (512 blocks for the small-N output proj) -------------
__global__ __launch_bounds__(256) void gemm_bt64(const short* __restrict__ A,
                                                 const short* __restrict__ BT,
                                                 float* __restrict__ C,
                                                 int M, int N, int K) {
    __shared__ short As[64 * 32];
    __shared__ short Bs[128 * 32];
    int tid  = threadIdx.x;
    int m0   = blockIdx.y * 64;
    int n0   = blockIdx.x * 128;
    int w    = tid >> 6, lane = tid & 63;
    int wm   = w >> 1,  wn   = w & 1;
    int quad = lane >> 4, l15 = lane & 15;
    int srow = lane >> 2;
    int scol = (lane & 3) * 8;

    float4v acc[2][4];
#pragma unroll
    for (int mi = 0; mi < 2; mi++)
#pragma unroll
        for (int ni = 0; ni < 4; ni++)
            acc[mi][ni] = {0.f, 0.f, 0.f, 0.f};

    for (int k0 = 0; k0 < K; k0 += 32) {
        __syncthreads();
        {
            int r = w * 16 + srow;
            gload_lds16(&A[(m0 + r) * K + k0 + scol], &As[w * 16 * 32]);
        }
#pragma unroll
        for (int t = 0; t < 2; t++) {
            int chunk = w * 2 + t;
            int r = chunk * 16 + srow;
            gload_lds16(&BT[(n0 + r) * K + k0 + scol], &Bs[chunk * 16 * 32]);
        }
        __syncthreads();
        short8 a[2], b[4];
#pragma unroll
        for (int mi = 0; mi < 2; mi++)
            a[mi] = *(const short8*)&As[(wm * 32 + mi * 16 + l15) * 32 + quad * 8];
#pragma unroll
        for (int ni = 0; ni < 4; ni++)
            b[ni] = *(const short8*)&Bs[(wn * 64 + ni * 16 + l15) * 32 + quad * 8];
#pragma unroll
        for (int mi = 0; mi < 2; mi++)
#pragma unroll
            for (int ni = 0; ni < 4; ni++)
                acc[mi][ni] = __builtin_amdgcn_mfma_f32_16x16x32_bf16(a[mi], b[ni], acc[mi][ni], 0, 0, 0);
    }

#pragma unroll
    for (int mi = 0; mi < 2; mi++)
#pragma unroll
        for (int ni = 0; ni < 4; ni++)
#pragma unroll
            for (int r = 0; r < 4; r++) {
                int row = m0 + wm * 32 + mi * 16 + quad * 4 + r;
                int col = n0 + wn * 64 + ni * 16 + l15;
                C[row * N + col] = acc[mi][ni][r];
            }
}

// ------------- flash attention, causal, bf16 MFMA, LDS-staged K/V (R8 winner) -------------
// Coalesced cooperative staging (R8: fixed the 64-line gather stall, 129->82 us).
// S^T register-P, raw v_exp_f32, k-permuted PV (swizzle baked into vt).
// XCD head pinning (grid h-major): FETCH 135->12 MB (R6).
__global__ __launch_bounds__(256) void attn_kernel(const short* __restrict__ qkv,
                                                   const short* __restrict__ vtp,
                                                   short* __restrict__ aout) {
    __shared__ short Ks[64 * 72];
    __shared__ short Vs[64 * 72];
    int h = blockIdx.x;              // 0..15  -> pins XCD = h%8
    int y = blockIdx.y;              // 0..31
    int t = (y < 16) ? (31 - y) : (y - 16);  // CU pairs (y, y+16): weights sum to 31
    int q0 = t * 128;
    int tid = threadIdx.x;
    int w = tid >> 6, lane = tid & 63;
    int quad = lane >> 4, l15 = lane & 15;
    int qw = q0 + w * 32;
    int r8 = lane >> 3, c8 = lane & 7;
    int srow = w * 16 + r8;          // this wave's staging rows: srow, srow+8

    const short* Kg = qkv + DM + h * HD;
    const short* Vg = vtp + (h * HD) * SEQ;

    short8 aq[2][2];
#pragma unroll
    for (int mi = 0; mi < 2; mi++)
#pragma unroll
        for (int kk = 0; kk < 2; kk++)
            aq[mi][kk] = *(const short8*)&qkv[(qw + mi * 16 + l15) * (3 * DM) + h * HD + kk * 32 + quad * 8];

    float lp[2] = {0.f, 0.f};
    float4v o[2][4];
#pragma unroll
    for (int mi = 0; mi < 2; mi++)
#pragma unroll
        for (int dt = 0; dt < 4; dt++)
            o[mi][dt] = {0.f, 0.f, 0.f, 0.f};

    int nTblk = 2 * t + 2;           // block-uniform tile count

    short8 kg[2], vg[2];
#pragma unroll
    for (int i = 0; i < 2; i++) {
        kg[i] = *(const short8*)&Kg[(srow + 8 * i) * (3 * DM) + c8 * 8];
        vg[i] = *(const short8*)&Vg[(srow + 8 * i) * SEQ + c8 * 8];
    }

    for (int tt = 0; tt < nTblk; tt++) {
        int s0 = tt * 64;
        int sn = (tt + 1 < nTblk) ? s0 + 64 : s0;

        __syncthreads();
#pragma unroll
        for (int i = 0; i < 2; i++) {
            *(short8*)&Ks[(srow + 8 * i) * 72 + c8 * 8] = kg[i];
            *(short8*)&Vs[(srow + 8 * i) * 72 + c8 * 8] = vg[i];
        }
#pragma unroll
        for (int i = 0; i < 2; i++) {
            kg[i] = *(const short8*)&Kg[(sn + srow + 8 * i) * (3 * DM) + c8 * 8];
            vg[i] = *(const short8*)&Vg[(srow + 8 * i) * SEQ + sn + c8 * 8];
        }
        __syncthreads();

        short8 kc[8], vc[8];
#pragma unroll
        for (int ni = 0; ni < 4; ni++)
#pragma unroll
            for (int kk = 0; kk < 2; kk++)
                kc[ni * 2 + kk] = *(const short8*)&Ks[(ni * 16 + l15) * 72 + kk * 32 + quad * 8];
#pragma unroll
        for (int dt = 0; dt < 4; dt++)
#pragma unroll
            for (int pr = 0; pr < 2; pr++)
                vc[dt * 2 + pr] = *(const short8*)&Vs[(dt * 16 + l15) * 72 + pr * 32 + quad * 8];

        float4v s[2][4];
#pragma unroll
        for (int mi = 0; mi < 2; mi++)
#pragma unroll
            for (int ni = 0; ni < 4; ni++) {
                float4v a = {0.f, 0.f, 0.f, 0.f};
#pragma unroll
                for (int kk = 0; kk < 2; kk++)
                    a = __builtin_amdgcn_mfma_f32_16x16x32_bf16(kc[ni * 2 + kk], aq[mi][kk], a, 0, 0, 0);
                s[mi][ni] = a;
            }

        bool diag = (s0 + 63 > qw);
        short8 pa[2][2];
#pragma unroll
        for (int mi = 0; mi < 2; mi++) {
            int qrow = qw + mi * 16 + l15;
#pragma unroll
            for (int ni = 0; ni < 4; ni++) {
#pragma unroll
                for (int r = 0; r < 4; r++) {
                    float p = __builtin_amdgcn_exp2f(s[mi][ni][r]);
                    if (diag) {
                        int scol = s0 + ni * 16 + quad * 4 + r;
                        p = (scol <= qrow) ? p : 0.f;
                    }
                    lp[mi] += p;
                    s[mi][ni][r] = p;
                }
            }
#pragma unroll
            for (int pr = 0; pr < 2; pr++) {
                int4v wpk;
                wpk[0] = pk2bf(s[mi][2 * pr][0], s[mi][2 * pr][1]);
                wpk[1] = pk2bf(s[mi][2 * pr][2], s[mi][2 * pr][3]);
                wpk[2] = pk2bf(s[mi][2 * pr + 1][0], s[mi][2 * pr + 1][1]);
                wpk[3] = pk2bf(s[mi][2 * pr + 1][2], s[mi][2 * pr + 1][3]);
                pa[mi][pr] = *(short8*)&wpk;
            }
        }
#pragma unroll
        for (int mi = 0; mi < 2; mi++)
#pragma unroll
            for (int dt = 0; dt < 4; dt++)
#pragma unroll
                for (int pr = 0; pr < 2; pr++)
                    o[mi][dt] = __builtin_amdgcn_mfma_f32_16x16x32_bf16(pa[mi][pr], vc[dt * 2 + pr], o[mi][dt], 0, 0, 0);
    }

#pragma unroll
    for (int mi = 0; mi < 2; mi++) {
        lp[mi] += __shfl_xor(lp[mi], 16, 64);
        lp[mi] += __shfl_xor(lp[mi], 32, 64);
    }
#pragma unroll
    for (int mi = 0; mi < 2; mi++)
#pragma unroll
        for (int r = 0; r < 4; r++) {
            float lr = __shfl(lp[mi], quad * 4 + r, 16);
            float inv = 1.0f / lr;
#pragma unroll
            for (int dt = 0; dt < 4; dt++) {
                float v = o[mi][dt][r] * inv;
                aout[(qw + mi * 16 + quad * 4 + r) * DM + h * HD + dt * 16 + l15] = f2bf(v);
            }
        }
}

extern "C" void kernel_launch(void* const* d_in, const int* in_sizes, int n_in,
                              void* d_out, int out_size, void* d_ws, size_t ws_size,
                              hipStream_t stream) {
    const float* x    = (const float*)d_in[0];
    const float* Wqkv = (const float*)d_in[1];
    const float* Wout = (const float*)d_in[2];
    float* out = (float*)d_out;

    char* ws = (char*)d_ws;
    short* xb    = (short*)(ws);                                 // 4096x1024 bf16   (8 MB)
    short* wqkvT = (short*)(ws + 8388608);                       // 3072x1024 bf16   (6 MB)
    short* woutT = (short*)(ws + 8388608 + 6291456);             // 1024x1024 bf16   (2 MB)
    short* qkv   = (short*)(ws + 16777216);                      // 4096x3072 bf16   (24 MB; V cols unused)
    short* vt    = (short*)(ws + 16777216 + 25165824);           // 16x64x4096 bf16  (8 MB, swizzled)
    short* ao    = (short*)(ws + 16777216 + 25165824 + 8388608); // 4096x1024 bf16   (8 MB)

    const float SC = 0.18033688011112042f;  // (1/sqrt(64)) * log2(e)

    prep_kernel<<<8192, 256, 0, stream>>>(x, Wqkv, Wout, xb, wqkvT, woutT, SC);

    gemm_qkv<<<dim3(3 * DM / 128, SEQ / 128), 256, 0, stream>>>(xb, wqkvT, qkv, vt);

    attn_kernel<<<dim3(NH, SEQ / 128), 256, 0, stream>>>(qkv, vt, ao);

    gemm_bt64<<<dim3(DM / 128, SEQ / 64), 256, 0, stream>>>(ao, woutT, out, SEQ, DM, DM);
}

// Round 10
// 224.274 us; speedup vs baseline: 1.0048x; 1.0048x over previous
//
#include <hip/hip_runtime.h>

#define SEQ 4096
#define DM 1024
#define NH 16
#define HD 64

typedef __attribute__((ext_vector_type(8))) short short8;
typedef __attribute__((ext_vector_type(4))) short short4v;
typedef __attribute__((ext_vector_type(2))) short short2v;
typedef __attribute__((ext_vector_type(4))) float float4v;
typedef __attribute__((ext_vector_type(4))) int int4v;

__device__ __forceinline__ short f2bf(float f) {
    union { float f; unsigned u; } v; v.f = f;
    unsigned u = v.u;
    return (short)((u + 0x7fffu + ((u >> 16) & 1u)) >> 16);
}
// pack two fp32 -> dword of two round-half-up bf16 (3 VALU: add, add, perm)
__device__ __forceinline__ int pk2bf(float a, float b) {
    union { float f; unsigned u; } x, y; x.f = a; y.f = b;
    return (int)__builtin_amdgcn_perm(y.u + 0x8000u, x.u + 0x8000u, 0x07060302u);
}

__device__ __forceinline__ void gload_lds16(const void* g, void* l) {
    __builtin_amdgcn_global_load_lds(
        (const __attribute__((address_space(1))) void*)g,
        (__attribute__((address_space(3))) void*)l, 16, 0, 0);
}

// ---------- prep: cast x -> bf16  +  transpose/cast both weights (one launch) ----------
// flat grid: [0,4096) cast_x ; [4096,7168) Wqkv^T (Q-cols prescaled) ; [7168,8192) Wout^T
__global__ __launch_bounds__(256) void prep_kernel(const float* __restrict__ x,
                                                   const float* __restrict__ Wqkv,
                                                   const float* __restrict__ Wout,
                                                   short* __restrict__ xb,
                                                   short* __restrict__ wqkvT,
                                                   short* __restrict__ woutT,
                                                   float qscale) {
    __shared__ float tile[32][33];
    int id = blockIdx.x;
    int tid = threadIdx.x;
    if (id < 4096) {
        int i = id * 256 + tid;            // n4 = SEQ*DM/4 = 1048576 exactly
        float4v v = ((const float4v*)x)[i];
        short4v o;
        o[0] = f2bf(v[0]); o[1] = f2bf(v[1]); o[2] = f2bf(v[2]); o[3] = f2bf(v[3]);
        ((short4v*)xb)[i] = o;
        return;
    }
    const float* in; short* outp; int H, W, sr; float sc; int gx, gy;
    if (id < 4096 + 3072) {
        int i2 = id - 4096;
        in = Wqkv; outp = wqkvT; H = DM; W = 3 * DM; sr = DM; sc = qscale;
        gx = i2 % 96; gy = i2 / 96;
    } else {
        int i3 = id - 7168;
        in = Wout; outp = woutT; H = DM; W = DM; sr = 0; sc = 1.0f;
        gx = i3 % 32; gy = i3 / 32;
    }
    int bx = gx * 32, by = gy * 32;
    int tx = tid & 31, ty = tid >> 5;      // 32 x 8
#pragma unroll
    for (int i = 0; i < 32; i += 8)
        tile[ty + i][tx] = in[(by + ty + i) * W + bx + tx];
    __syncthreads();
#pragma unroll
    for (int i = 0; i < 32; i += 8) {
        int orow = bx + ty + i;
        float s = (orow < sr) ? sc : 1.0f;
        outp[orow * H + by + tx] = f2bf(tile[tx][ty + i] * s);
    }
}

// ------------- GEMM1: xb[4096,1024] x wqkvT[3072,1024] -> qkv (Q,K cols) + vt (V cols) --
// m97 structure, 128x128 tile. V columns (n0>=2048) go to the swizzled vt layout through
// an LDS-staged transposed epilogue: direct scatter stores (R9) hit 64 lines per store
// instruction (8KB lane stride); staging + s-direction cooperative writes cut that ~8x.
__global__ __launch_bounds__(256) void gemm_qkv(const short* __restrict__ A,
                                                const short* __restrict__ BT,
                                                short* __restrict__ C,
                                                short* __restrict__ vt) {
    const int K = DM, N = 3 * DM;
    __shared__ short As[128 * 32];
    __shared__ short Bs[128 * 32];
    __shared__ short Vt[64 * 136];   // [dcol 64][s 128 + pad 8]
    int tid  = threadIdx.x;
    int m0   = blockIdx.y * 128;
    int n0   = blockIdx.x * 128;
    int w    = tid >> 6, lane = tid & 63;
    int wm   = w >> 1,  wn   = w & 1;
    int quad = lane >> 4, l15 = lane & 15;
    int srow = lane >> 2;
    int scol = (lane & 3) * 8;

    float4v acc[4][4];
#pragma unroll
    for (int mi = 0; mi < 4; mi++)
#pragma unroll
        for (int ni = 0; ni < 4; ni++)
            acc[mi][ni] = {0.f, 0.f, 0.f, 0.f};

    for (int k0 = 0; k0 < K; k0 += 32) {
        __syncthreads();
#pragma unroll
        for (int t = 0; t < 2; t++) {
            int chunk = w * 2 + t;
            int r = chunk * 16 + srow;
            gload_lds16(&A[(m0 + r) * K + k0 + scol], &As[chunk * 16 * 32]);
            gload_lds16(&BT[(n0 + r) * K + k0 + scol], &Bs[chunk * 16 * 32]);
        }
        __syncthreads();
        short8 a[4], b[4];
#pragma unroll
        for (int mi = 0; mi < 4; mi++)
            a[mi] = *(const short8*)&As[(wm * 64 + mi * 16 + l15) * 32 + quad * 8];
#pragma unroll
        for (int ni = 0; ni < 4; ni++)
            b[ni] = *(const short8*)&Bs[(wn * 64 + ni * 16 + l15) * 32 + quad * 8];
#pragma unroll
        for (int mi = 0; mi < 4; mi++)
#pragma unroll
            for (int ni = 0; ni < 4; ni++)
                acc[mi][ni] = __builtin_amdgcn_mfma_f32_16x16x32_bf16(a[mi], b[ni], acc[mi][ni], 0, 0, 0);
    }

    if (n0 < 2 * DM) {
        // Q,K columns -> qkv row-major (coalesced: col = ..+l15)
#pragma unroll
        for (int mi = 0; mi < 4; mi++)
#pragma unroll
            for (int ni = 0; ni < 4; ni++)
#pragma unroll
                for (int r = 0; r < 4; r++) {
                    int row = m0 + wm * 64 + mi * 16 + quad * 4 + r;
                    int col = n0 + wn * 64 + ni * 16 + l15;
                    C[row * N + col] = f2bf(acc[mi][ni][r]);
                }
    } else {
        // V columns: LDS-staged transpose, then coalesced swizzled writes
#pragma unroll
        for (int half = 0; half < 2; half++) {
            __syncthreads();
            if (wn == half) {
#pragma unroll
                for (int mi = 0; mi < 4; mi++)
#pragma unroll
                    for (int ni = 0; ni < 4; ni++) {
                        int drow  = ni * 16 + l15;              // 0..63
                        int sbase = wm * 64 + mi * 16 + quad * 4;
                        short4v pv;
#pragma unroll
                        for (int r = 0; r < 4; r++)
                            pv[r] = f2bf(acc[mi][ni][r]);
                        *(short4v*)&Vt[drow * 136 + sbase] = pv;
                    }
            }
            __syncthreads();
            // write out: 16 lanes cover one dcol row's 128 s (256B, swz permutes within 64B)
#pragma unroll
            for (int p = 0; p < 4; p++) {
                int drow  = p * 16 + (tid >> 4);
                int chunk = tid & 15;                           // 8 shorts each
                int sl    = chunk * 8;
                int sg    = m0 + sl;                            // sg & 7 == 0
                int swz0  = (sg & ~31) | ((sg & 12) << 1) | ((sg & 16) >> 2);
                int sg1   = sg + 4;
                int swz1  = (sg1 & ~31) | ((sg1 & 12) << 1) | ((sg1 & 16) >> 2);
                int dcolg = n0 - 2 * DM + half * 64 + drow;
                short4v a0 = *(const short4v*)&Vt[drow * 136 + sl];
                short4v a1 = *(const short4v*)&Vt[drow * 136 + sl + 4];
                *(short4v*)&vt[dcolg * SEQ + swz0] = a0;
                *(short4v*)&vt[dcolg * SEQ + swz1] = a1;
            }
        }
    }
}

// ------------- GEMM2: 64x128 tile (512 blocks for the small-N output proj) -------------
__global__ __launch_bounds__(256) void gemm_bt64(const short* __restrict__ A,
                                                 const short* __restrict__ BT,
                                                 float* __restrict__ C,
                                                 int M, int N, int K) {
    __shared__ short As[64 * 32];
    __shared__ short Bs[128 * 32];
    int tid  = threadIdx.x;
    int m0   = blockIdx.y * 64;
    int n0   = blockIdx.x * 128;
    int w    = tid >> 6, lane = tid & 63;
    int wm   = w >> 1,  wn   = w & 1;
    int quad = lane >> 4, l15 = lane & 15;
    int srow = lane >> 2;
    int scol = (lane & 3) * 8;

    float4v acc[2][4];
#pragma unroll
    for (int mi = 0; mi < 2; mi++)
#pragma unroll
        for (int ni = 0; ni < 4; ni++)
            acc[mi][ni] = {0.f, 0.f, 0.f, 0.f};

    for (int k0 = 0; k0 < K; k0 += 32) {
        __syncthreads();
        {
            int r = w * 16 + srow;
            gload_lds16(&A[(m0 + r) * K + k0 + scol], &As[w * 16 * 32]);
        }
#pragma unroll
        for (int t = 0; t < 2; t++) {
            int chunk = w * 2 + t;
            int r = chunk * 16 + srow;
            gload_lds16(&BT[(n0 + r) * K + k0 + scol], &Bs[chunk * 16 * 32]);
        }
        __syncthreads();
        short8 a[2], b[4];
#pragma unroll
        for (int mi = 0; mi < 2; mi++)
            a[mi] = *(const short8*)&As[(wm * 32 + mi * 16 + l15) * 32 + quad * 8];
#pragma unroll
        for (int ni = 0; ni < 4; ni++)
            b[ni] = *(const short8*)&Bs[(wn * 64 + ni * 16 + l15) * 32 + quad * 8];
#pragma unroll
        for (int mi = 0; mi < 2; mi++)
#pragma unroll
            for (int ni = 0; ni < 4; ni++)
                acc[mi][ni] = __builtin_amdgcn_mfma_f32_16x16x32_bf16(a[mi], b[ni], acc[mi][ni], 0, 0, 0);
    }

#pragma unroll
    for (int mi = 0; mi < 2; mi++)
#pragma unroll
        for (int ni = 0; ni < 4; ni++)
#pragma unroll
            for (int r = 0; r < 4; r++) {
                int row = m0 + wm * 32 + mi * 16 + quad * 4 + r;
                int col = n0 + wn * 64 + ni * 16 + l15;
                C[row * N + col] = acc[mi][ni][r];
            }
}

// ------------- flash attention, causal, bf16 MFMA, LDS-staged K/V (R8 winner) -------------
// Coalesced cooperative staging (R8: fixed the 64-line gather stall, 129->82 us).
// S^T register-P, raw v_exp_f32, k-permuted PV (swizzle baked into vt).
// XCD head pinning (grid h-major): FETCH 135->12 MB (R6).
__global__ __launch_bounds__(256) void attn_kernel(const short* __restrict__ qkv,
                                                   const short* __restrict__ vtp,
                                                   short* __restrict__ aout) {
    __shared__ short Ks[64 * 72];
    __shared__ short Vs[64 * 72];
    int h = blockIdx.x;              // 0..15  -> pins XCD = h%8
    int y = blockIdx.y;              // 0..31
    int t = (y < 16) ? (31 - y) : (y - 16);  // CU pairs (y, y+16): weights sum to 31
    int q0 = t * 128;
    int tid = threadIdx.x;
    int w = tid >> 6, lane = tid & 63;
    int quad = lane >> 4, l15 = lane & 15;
    int qw = q0 + w * 32;
    int r8 = lane >> 3, c8 = lane & 7;
    int srow = w * 16 + r8;          // this wave's staging rows: srow, srow+8

    const short* Kg = qkv + DM + h * HD;
    const short* Vg = vtp + (h * HD) * SEQ;

    short8 aq[2][2];
#pragma unroll
    for (int mi = 0; mi < 2; mi++)
#pragma unroll
        for (int kk = 0; kk < 2; kk++)
            aq[mi][kk] = *(const short8*)&qkv[(qw + mi * 16 + l15) * (3 * DM) + h * HD + kk * 32 + quad * 8];

    float lp[2] = {0.f, 0.f};
    float4v o[2][4];
#pragma unroll
    for (int mi = 0; mi < 2; mi++)
#pragma unroll
        for (int dt = 0; dt < 4; dt++)
            o[mi][dt] = {0.f, 0.f, 0.f, 0.f};

    int nTblk = 2 * t + 2;           // block-uniform tile count

    short8 kg[2], vg[2];
#pragma unroll
    for (int i = 0; i < 2; i++) {
        kg[i] = *(const short8*)&Kg[(srow + 8 * i) * (3 * DM) + c8 * 8];
        vg[i] = *(const short8*)&Vg[(srow + 8 * i) * SEQ + c8 * 8];
    }

    for (int tt = 0; tt < nTblk; tt++) {
        int s0 = tt * 64;
        int sn = (tt + 1 < nTblk) ? s0 + 64 : s0;

        __syncthreads();
#pragma unroll
        for (int i = 0; i < 2; i++) {
            *(short8*)&Ks[(srow + 8 * i) * 72 + c8 * 8] = kg[i];
            *(short8*)&Vs[(srow + 8 * i) * 72 + c8 * 8] = vg[i];
        }
#pragma unroll
        for (int i = 0; i < 2; i++) {
            kg[i] = *(const short8*)&Kg[(sn + srow + 8 * i) * (3 * DM) + c8 * 8];
            vg[i] = *(const short8*)&Vg[(srow + 8 * i) * SEQ + sn + c8 * 8];
        }
        __syncthreads();

        short8 kc[8], vc[8];
#pragma unroll
        for (int ni = 0; ni < 4; ni++)
#pragma unroll
            for (int kk = 0; kk < 2; kk++)
                kc[ni * 2 + kk] = *(const short8*)&Ks[(ni * 16 + l15) * 72 + kk * 32 + quad * 8];
#pragma unroll
        for (int dt = 0; dt < 4; dt++)
#pragma unroll
            for (int pr = 0; pr < 2; pr++)
                vc[dt * 2 + pr] = *(const short8*)&Vs[(dt * 16 + l15) * 72 + pr * 32 + quad * 8];

        float4v s[2][4];
#pragma unroll
        for (int mi = 0; mi < 2; mi++)
#pragma unroll
            for (int ni = 0; ni < 4; ni++) {
                float4v a = {0.f, 0.f, 0.f, 0.f};
#pragma unroll
                for (int kk = 0; kk < 2; kk++)
                    a = __builtin_amdgcn_mfma_f32_16x16x32_bf16(kc[ni * 2 + kk], aq[mi][kk], a, 0, 0, 0);
                s[mi][ni] = a;
            }

        bool diag = (s0 + 63 > qw);
        short8 pa[2][2];
#pragma unroll
        for (int mi = 0; mi < 2; mi++) {
            int qrow = qw + mi * 16 + l15;
#pragma unroll
            for (int ni = 0; ni < 4; ni++) {
#pragma unroll
                for (int r = 0; r < 4; r++) {
                    float p = __builtin_amdgcn_exp2f(s[mi][ni][r]);
                    if (diag) {
                        int scol = s0 + ni * 16 + quad * 4 + r;
                        p = (scol <= qrow) ? p : 0.f;
                    }
                    lp[mi] += p;
                    s[mi][ni][r] = p;
                }
            }
#pragma unroll
            for (int pr = 0; pr < 2; pr++) {
                int4v wpk;
                wpk[0] = pk2bf(s[mi][2 * pr][0], s[mi][2 * pr][1]);
                wpk[1] = pk2bf(s[mi][2 * pr][2], s[mi][2 * pr][3]);
                wpk[2] = pk2bf(s[mi][2 * pr + 1][0], s[mi][2 * pr + 1][1]);
                wpk[3] = pk2bf(s[mi][2 * pr + 1][2], s[mi][2 * pr + 1][3]);
                pa[mi][pr] = *(short8*)&wpk;
            }
        }
#pragma unroll
        for (int mi = 0; mi < 2; mi++)
#pragma unroll
            for (int dt = 0; dt < 4; dt++)
#pragma unroll
                for (int pr = 0; pr < 2; pr++)
                    o[mi][dt] = __builtin_amdgcn_mfma_f32_16x16x32_bf16(pa[mi][pr], vc[dt * 2 + pr], o[mi][dt], 0, 0, 0);
    }

#pragma unroll
    for (int mi = 0; mi < 2; mi++) {
        lp[mi] += __shfl_xor(lp[mi], 16, 64);
        lp[mi] += __shfl_xor(lp[mi], 32, 64);
    }
#pragma unroll
    for (int mi = 0; mi < 2; mi++)
#pragma unroll
        for (int r = 0; r < 4; r++) {
            float lr = __shfl(lp[mi], quad * 4 + r, 16);
            float inv = 1.0f / lr;
#pragma unroll
            for (int dt = 0; dt < 4; dt++) {
                float v = o[mi][dt][r] * inv;
                aout[(qw + mi * 16 + quad * 4 + r) * DM + h * HD + dt * 16 + l15] = f2bf(v);
            }
        }
}

extern "C" void kernel_launch(void* const* d_in, const int* in_sizes, int n_in,
                              void* d_out, int out_size, void* d_ws, size_t ws_size,
                              hipStream_t stream) {
    const float* x    = (const float*)d_in[0];
    const float* Wqkv = (const float*)d_in[1];
    const float* Wout = (const float*)d_in[2];
    float* out = (float*)d_out;

    char* ws = (char*)d_ws;
    short* xb    = (short*)(ws);                                 // 4096x1024 bf16   (8 MB)
    short* wqkvT = (short*)(ws + 8388608);                       // 3072x1024 bf16   (6 MB)
    short* woutT = (short*)(ws + 8388608 + 6291456);             // 1024x1024 bf16   (2 MB)
    short* qkv   = (short*)(ws + 16777216);                      // 4096x3072 bf16   (24 MB; V cols unused)
    short* vt    = (short*)(ws + 16777216 + 25165824);           // 16x64x4096 bf16  (8 MB, swizzled)
    short* ao    = (short*)(ws + 16777216 + 25165824 + 8388608); // 4096x1024 bf16   (8 MB)

    const float SC = 0.18033688011112042f;  // (1/sqrt(64)) * log2(e)

    prep_kernel<<<8192, 256, 0, stream>>>(x, Wqkv, Wout, xb, wqkvT, woutT, SC);

    gemm_qkv<<<dim3(3 * DM / 128, SEQ / 128), 256, 0, stream>>>(xb, wqkvT, qkv, vt);

    attn_kernel<<<dim3(NH, SEQ / 128), 256, 0, stream>>>(qkv, vt, ao);

    gemm_bt64<<<dim3(DM / 128, SEQ / 64), 256, 0, stream>>>(ao, woutT, out, SEQ, DM, DM);
}